// Round 13
// baseline (276.386 us; speedup 1.0000x reference)
//
#include <hip/hip_runtime.h>
#include <hip/hip_bf16.h>

static constexpr int BB   = 32;
static constexpr int TKK  = 1024;
static constexpr int ND   = 1024;   // N = 2*H
static constexpr int ADIM = 512;

typedef __attribute__((ext_vector_type(8))) short bf16x8;
typedef __attribute__((ext_vector_type(4))) float f32x4;

__device__ __forceinline__ float fast_tanh(float x) {
  x = fminf(fmaxf(x, -15.f), 15.f);
  float e = __expf(2.f * x);
  return __fdividef(e - 1.f, e + 1.f);
}

__device__ __forceinline__ short f2bf(float x) {  // RNE f32->bf16
  unsigned u = __float_as_uint(x);
  u += 0x7FFF + ((u >> 16) & 1);
  return (short)(u >> 16);
}

__device__ __forceinline__ void gload_lds16(const void* g, void* l) {
  __builtin_amdgcn_global_load_lds(
      (const __attribute__((address_space(1))) unsigned int*)g,
      (__attribute__((address_space(3))) unsigned int*)l, 16, 0, 0);
}

// K0: f32 -> bf16 streaming convert for r_i (8192 blocks) and Wr (256 blocks).
__global__ __launch_bounds__(256) void k_cvt2(const float* __restrict__ r_i,
    const float* __restrict__ Wr, short* __restrict__ rb, short* __restrict__ wb) {
  size_t bid = blockIdx.x;
  const float* src;
  short* dst;
  size_t i;
  if (bid < 8192) { src = r_i; dst = rb; i = bid * 256 + threadIdx.x; }
  else            { src = Wr;  dst = wb; i = (bid - 8192) * 256 + threadIdx.x; }
  float4 a = ((const float4*)src)[2 * i];
  float4 b = ((const float4*)src)[2 * i + 1];
  bf16x8 h;
  h[0] = f2bf(a.x); h[1] = f2bf(a.y); h[2] = f2bf(a.z); h[3] = f2bf(a.w);
  h[4] = f2bf(b.x); h[5] = f2bf(b.y); h[6] = f2bf(b.z); h[7] = f2bf(b.w);
  ((bf16x8*)dst)[i] = h;
}

// K1: dec[b][n] = sum_k s_t_hat[b][k] * Wsw[n][k] + Wsb[n]
__global__ __launch_bounds__(256) void k_decfea(const float* __restrict__ s_t_hat,
    const float* __restrict__ Wsw, const float* __restrict__ Wsb,
    float* __restrict__ dec) {
  int b  = blockIdx.x >> 3;
  int n0 = (blockIdx.x & 7) << 7;
  int w = threadIdx.x >> 6, lane = threadIdx.x & 63;
  const float4* s4 = (const float4*)(s_t_hat + (size_t)b * ND);
  float4 sv0 = s4[lane], sv1 = s4[lane + 64], sv2 = s4[lane + 128], sv3 = s4[lane + 192];
  for (int nn = 0; nn < 32; nn++) {
    int n = n0 + w * 32 + nn;
    const float4* w4 = (const float4*)(Wsw + (size_t)n * ND);
    float4 wa = w4[lane], wb = w4[lane + 64], wc = w4[lane + 128], wd = w4[lane + 192];
    float acc = sv0.x*wa.x + sv0.y*wa.y + sv0.z*wa.z + sv0.w*wa.w
              + sv1.x*wb.x + sv1.y*wb.y + sv1.z*wb.z + sv1.w*wb.w
              + sv2.x*wc.x + sv2.y*wc.y + sv2.z*wc.z + sv2.w*wc.w
              + sv3.x*wd.x + sv3.y*wd.y + sv3.z*wd.z + sv3.w*wd.w;
    #pragma unroll
    for (int off = 32; off; off >>= 1) acc += __shfl_down(acc, off);
    if (lane == 0) dec[b * ND + n] = acc + Wsb[n];
  }
}

// K2: wave-per-row scores: 4 rows/block, in-wave reduce, no LDS/syncthreads.
__global__ __launch_bounds__(256) void k_scoresA(const float* __restrict__ ef,
    const float* __restrict__ dec, const float* __restrict__ Wc,
    const float* __restrict__ vw, const float* __restrict__ cov,
    float* __restrict__ scores) {
  const int bt = blockIdx.x * 4 + (threadIdx.x >> 6);
  const int b  = bt >> 10;
  const int lane = threadIdx.x & 63;
  const float c = cov[bt];
  float s = 0.f;
  #pragma unroll
  for (int q = 0; q < 4; ++q) {
    const int col = q * 256 + lane * 4;
    float4 e = *(const float4*)(ef + (size_t)bt * ND + col);
    float4 d = *(const float4*)(dec + (size_t)b * ND + col);
    float4 w = *(const float4*)(Wc + col);
    float4 v = *(const float4*)(vw + col);
    s += v.x * fast_tanh(e.x + d.x + c * w.x)
       + v.y * fast_tanh(e.y + d.y + c * w.y)
       + v.z * fast_tanh(e.z + d.z + c * w.z)
       + v.w * fast_tanh(e.w + d.w + c * w.w);
  }
  #pragma unroll
  for (int off = 32; off; off >>= 1) s += __shfl_down(s, off);
  if (lane == 0) scores[bt] = s;
}

// K3: attn = e^{s-max}*mask / sum(e^{s-max}*mask);  covnew = cov + attn
__global__ __launch_bounds__(256) void k_softmaxA(const float* __restrict__ scores,
    const float* __restrict__ mask, const float* __restrict__ cov,
    float* __restrict__ attn, float* __restrict__ covnew) {
  __shared__ float sb[4];
  int b = blockIdx.x, tid = threadIdx.x;
  float4 s = *(const float4*)(scores + (size_t)b * TKK + tid * 4);
  float m = fmaxf(fmaxf(s.x, s.y), fmaxf(s.z, s.w));
  #pragma unroll
  for (int off = 32; off; off >>= 1) m = fmaxf(m, __shfl_down(m, off));
  if ((tid & 63) == 0) sb[tid >> 6] = m;
  __syncthreads();
  m = fmaxf(fmaxf(sb[0], sb[1]), fmaxf(sb[2], sb[3]));
  float4 mk = *(const float4*)(mask + (size_t)b * TKK + tid * 4);
  float4 e;
  e.x = __expf(s.x - m) * mk.x;
  e.y = __expf(s.y - m) * mk.y;
  e.z = __expf(s.z - m) * mk.z;
  e.w = __expf(s.w - m) * mk.w;
  float sum = e.x + e.y + e.z + e.w;
  #pragma unroll
  for (int off = 32; off; off >>= 1) sum += __shfl_down(sum, off);
  __syncthreads();
  if ((tid & 63) == 0) sb[tid >> 6] = sum;
  __syncthreads();
  float inv = __fdividef(1.f, sb[0] + sb[1] + sb[2] + sb[3]);
  float4 a = {e.x * inv, e.y * inv, e.z * inv, e.w * inv};
  *(float4*)(attn + (size_t)b * TKK + tid * 4) = a;
  float4 c = *(const float4*)(cov + (size_t)b * TKK + tid * 4);
  float4 cn = {c.x + a.x, c.y + a.y, c.z + a.z, c.w + a.w};
  *(float4*)(covnew + (size_t)b * TKK + tid * 4) = cn;
}

// K4 (A-resident): block = 64 t-rows x ALL 1024 cols, 4 waves, grid 512
// (= exactly 2 blocks/CU, one generation). A-tile (64x512 = 64 KB) preloaded
// to LDS ONCE (0-conflict sub-tile swizzle); B streamed global->reg, L2-hot
// (1 MB reread per block). One barrier total; no barriers in compute.
// Each wave owns 4 col-chunks of 64, processed sequentially with acc reuse.
__global__ __launch_bounds__(256) void k_gemmB7(const short* __restrict__ rb,
    const short* __restrict__ wb, const float* __restrict__ dec,
    const float* __restrict__ vw, float* __restrict__ part) {
  __shared__ __align__(16) short Al[16 * 64 * 32];   // [kc][row][32] = 64 KB
  const int tid = threadIdx.x;
  const int lane = tid & 63, wv = tid >> 6;          // 4 waves
  const int g = lane >> 4, cl = lane & 15;
  const int bid = blockIdx.x;                        // 512 blocks
  const int b  = bid >> 4;
  const int t0 = (bid & 15) * 64;
  const short* Ag = rb + (size_t)(b * TKK + t0) * ADIM;
  const int lrow4 = lane >> 2;                               // 0..15
  const int sck   = ((lane & 3) ^ ((lane >> 3) & 3)) * 8;    // src chunk swizzle
  const int rdsw  = (g ^ ((cl >> 1) & 3)) * 8;               // read-side phys chunk

  // ---- one-time A preload: 64 sub-stages (16 rows x one kc), 16 per wave
  #pragma unroll
  for (int j = 0; j < 16; ++j) {
    const int p  = wv * 16 + j;               // 0..63
    const int rc = (p >> 4) * 16;             // row group 0/16/32/48
    const int kc = p & 15;                    // k sub-tile
    gload_lds16(Ag + (size_t)(rc + lrow4) * ADIM + kc * 32 + sck,
                &Al[(kc * 64 + rc) * 32]);
  }
  asm volatile("s_waitcnt vmcnt(0)" ::: "memory");
  __builtin_amdgcn_s_barrier();              // the only barrier

  const int browg = b * TKK + t0;

  for (int j = 0; j < 4; ++j) {              // wave's 4 col-chunks
    const int chunk = wv * 4 + j;
    const int n0 = chunk * 64;
    const short* Bp[4];
    #pragma unroll
    for (int n = 0; n < 4; ++n)
      Bp[n] = wb + (size_t)(n0 + n * 16 + cl) * ADIM + g * 8;

    f32x4 acc[4][4];
    #pragma unroll
    for (int m = 0; m < 4; ++m)
      #pragma unroll
      for (int n = 0; n < 4; ++n) acc[m][n] = (f32x4){0.f, 0.f, 0.f, 0.f};

    #pragma unroll
    for (int kc = 0; kc < 16; ++kc) {
      bf16x8 bfr[4], af[4];
      #pragma unroll
      for (int n = 0; n < 4; ++n)
        bfr[n] = *(const bf16x8*)(Bp[n] + kc * 32);
      #pragma unroll
      for (int m = 0; m < 4; ++m)
        af[m] = *(const bf16x8*)&Al[(kc * 64 + m * 16 + cl) * 32 + rdsw];
      #pragma unroll
      for (int m = 0; m < 4; ++m)
        #pragma unroll
        for (int n = 0; n < 4; ++n)
          acc[m][n] = __builtin_amdgcn_mfma_f32_16x16x32_bf16(
              af[m], bfr[n], acc[m][n], 0, 0, 0);
    }

    // epilogue for this chunk: C/D layout col=lane&15, row=(lane>>4)*4+reg
    float vvv[4], ddd[4];
    #pragma unroll
    for (int n = 0; n < 4; ++n) {
      const int col = n0 + n * 16 + cl;
      vvv[n] = vw[col];
      ddd[n] = dec[b * ND + col];
    }
    #pragma unroll
    for (int m = 0; m < 4; ++m) {
      #pragma unroll
      for (int r = 0; r < 4; ++r) {
        float s = 0.f;
        #pragma unroll
        for (int n = 0; n < 4; ++n)
          s += vvv[n] * fast_tanh(acc[m][n][r] + ddd[n]);
        #pragma unroll
        for (int off = 1; off < 16; off <<= 1) s += __shfl_xor(s, off);
        if (cl == 0) {
          const int rowg = browg + m * 16 + g * 4 + r;
          part[(size_t)rowg * 16 + chunk] = s;
        }
      }
    }
  }
}

// K4 fallback (reg-staged cvt in-kernel) — used only if ws too small for bf16 copies.
__global__ __launch_bounds__(256) void k_gemmB(const float* __restrict__ r_i,
    const float* __restrict__ Wr, const float* __restrict__ dec,
    const float* __restrict__ vw, float* __restrict__ part) {
  __shared__ short As[128 * 64];
  __shared__ short Bs[128 * 64];
  const int tid = threadIdx.x;
  const int lane = tid & 63, wv = tid >> 6;
  const int wm = wv >> 1, wn = wv & 1;
  const int g = lane >> 4, cl = lane & 15;
  const int mchunk = blockIdx.x, nchunk = blockIdx.y;
  const int b  = mchunk >> 3;
  const int t0 = (mchunk & 7) * 128;
  const int n0 = nchunk * 128;
  const float* Ag = r_i + (size_t)(b * TKK + t0) * ADIM;
  const float* Bg = Wr + (size_t)n0 * ADIM;
  const int srow = tid >> 3, skk = (tid & 7) * 8;

  f32x4 acc[4][4];
  #pragma unroll
  for (int m = 0; m < 4; ++m)
    #pragma unroll
    for (int n = 0; n < 4; ++n) acc[m][n] = (f32x4){0.f, 0.f, 0.f, 0.f};

  for (int kc = 0; kc < 8; ++kc) {
    const int k0 = kc * 64;
    __syncthreads();
    #pragma unroll
    for (int dit = 0; dit < 4; ++dit) {
      const int row = dit * 32 + srow;
      const float* sa = Ag + (size_t)row * ADIM + k0 + skk;
      float4 a0 = *(const float4*)sa, a1 = *(const float4*)(sa + 4);
      bf16x8 ha;
      ha[0]=f2bf(a0.x); ha[1]=f2bf(a0.y); ha[2]=f2bf(a0.z); ha[3]=f2bf(a0.w);
      ha[4]=f2bf(a1.x); ha[5]=f2bf(a1.y); ha[6]=f2bf(a1.z); ha[7]=f2bf(a1.w);
      *(bf16x8*)&As[row * 64 + skk] = ha;
      const float* sbp = Bg + (size_t)row * ADIM + k0 + skk;
      float4 b0 = *(const float4*)sbp, b1 = *(const float4*)(sbp + 4);
      bf16x8 hb;
      hb[0]=f2bf(b0.x); hb[1]=f2bf(b0.y); hb[2]=f2bf(b0.z); hb[3]=f2bf(b0.w);
      hb[4]=f2bf(b1.x); hb[5]=f2bf(b1.y); hb[6]=f2bf(b1.z); hb[7]=f2bf(b1.w);
      *(bf16x8*)&Bs[row * 64 + skk] = hb;
    }
    __syncthreads();
    #pragma unroll
    for (int kf = 0; kf < 2; ++kf) {
      bf16x8 af[4], bfr[4];
      #pragma unroll
      for (int m = 0; m < 4; ++m)
        af[m] = *(const bf16x8*)&As[(wm * 64 + m * 16 + cl) * 64 + kf * 32 + g * 8];
      #pragma unroll
      for (int n = 0; n < 4; ++n)
        bfr[n] = *(const bf16x8*)&Bs[(wn * 64 + n * 16 + cl) * 64 + kf * 32 + g * 8];
      #pragma unroll
      for (int m = 0; m < 4; ++m)
        #pragma unroll
        for (int n = 0; n < 4; ++n)
          acc[m][n] = __builtin_amdgcn_mfma_f32_16x16x32_bf16(af[m], bfr[n], acc[m][n], 0, 0, 0);
    }
  }
  float vvv[4], ddd[4];
  #pragma unroll
  for (int n = 0; n < 4; ++n) {
    const int col = n0 + wn * 64 + n * 16 + cl;
    vvv[n] = vw[col];
    ddd[n] = dec[b * ND + col];
  }
  #pragma unroll
  for (int m = 0; m < 4; ++m) {
    #pragma unroll
    for (int r = 0; r < 4; ++r) {
      float s = 0.f;
      #pragma unroll
      for (int n = 0; n < 4; ++n)
        s += vvv[n] * fast_tanh(acc[m][n][r] + ddd[n]);
      #pragma unroll
      for (int off = 1; off < 16; off <<= 1) s += __shfl_xor(s, off);
      if (cl == 0) {
        const int rowg = b * TKK + t0 + wm * 64 + m * 16 + g * 4 + r;
        part[(size_t)rowg * 16 + nchunk * 2 + wn] = s;
      }
    }
  }
}

// K5: s2 = sum of 16 partials; a_struct = e^{s2-max}*mask / sum(e^{s2-max})
__global__ __launch_bounds__(256) void k_softmaxB(const float* __restrict__ part,
    const float* __restrict__ mask, float* __restrict__ astruct) {
  __shared__ float sb[4];
  int b = blockIdx.x, tid = threadIdx.x;
  float sv[4];
  #pragma unroll
  for (int tt = 0; tt < 4; ++tt) {
    const float4* pp = (const float4*)(part + ((size_t)b * TKK + tid * 4 + tt) * 16);
    float4 q0 = pp[0], q1 = pp[1], q2 = pp[2], q3 = pp[3];
    sv[tt] = q0.x+q0.y+q0.z+q0.w + q1.x+q1.y+q1.z+q1.w
           + q2.x+q2.y+q2.z+q2.w + q3.x+q3.y+q3.z+q3.w;
  }
  float m = fmaxf(fmaxf(sv[0], sv[1]), fmaxf(sv[2], sv[3]));
  #pragma unroll
  for (int off = 32; off; off >>= 1) m = fmaxf(m, __shfl_down(m, off));
  if ((tid & 63) == 0) sb[tid >> 6] = m;
  __syncthreads();
  m = fmaxf(fmaxf(sb[0], sb[1]), fmaxf(sb[2], sb[3]));
  float e0 = __expf(sv[0] - m), e1 = __expf(sv[1] - m);
  float e2 = __expf(sv[2] - m), e3 = __expf(sv[3] - m);
  float sum = e0 + e1 + e2 + e3;
  #pragma unroll
  for (int off = 32; off; off >>= 1) sum += __shfl_down(sum, off);
  __syncthreads();
  if ((tid & 63) == 0) sb[tid >> 6] = sum;
  __syncthreads();
  float inv = __fdividef(1.f, sb[0] + sb[1] + sb[2] + sb[3]);
  float4 mk = *(const float4*)(mask + (size_t)b * TKK + tid * 4);
  float4 a = {e0 * mk.x * inv, e1 * mk.y * inv, e2 * mk.z * inv, e3 * mk.w * inv};
  *(float4*)(astruct + (size_t)b * TKK + tid * 4) = a;
}

// K6: partial contexts over t-chunks of 128; both attention vectors, one enc pass.
__global__ __launch_bounds__(256) void k_ctx(const float* __restrict__ enc,
    const float* __restrict__ attn, const float* __restrict__ astr,
    float* __restrict__ partials) {
  int tc = blockIdx.x, b = blockIdx.y;     // tc 0..7
  int tid = threadIdx.x, lane = tid & 63;
  const float4* e4 = (const float4*)(enc + (size_t)(b * TKK + tc * 128) * ND);
  float4 ac = {0, 0, 0, 0}, as = {0, 0, 0, 0};
  #pragma unroll
  for (int h = 0; h < 2; ++h) {
    float a1v = attn[(size_t)b * TKK + tc * 128 + h * 64 + lane];
    float a2v = astr[(size_t)b * TKK + tc * 128 + h * 64 + lane];
    #pragma unroll 4
    for (int m = 0; m < 64; m++) {
      float a1 = __shfl(a1v, m), a2 = __shfl(a2v, m);
      float4 ev = e4[(size_t)(h * 64 + m) * 256 + tid];
      ac.x += a1 * ev.x; ac.y += a1 * ev.y; ac.z += a1 * ev.z; ac.w += a1 * ev.w;
      as.x += a2 * ev.x; as.y += a2 * ev.y; as.z += a2 * ev.z; as.w += a2 * ev.w;
    }
  }
  float* p = partials + (size_t)(b * 8 + tc) * 2 * ND;
  *(float4*)(p + tid * 4) = ac;
  *(float4*)(p + ND + tid * 4) = as;
}

// K7: sum 8 t-chunk partials -> c_t, c_t_struct
__global__ __launch_bounds__(256) void k_reduce(const float* __restrict__ partials,
    float* __restrict__ ct, float* __restrict__ cts) {
  int b = blockIdx.x, tid = threadIdx.x;
  float4 sc = {0, 0, 0, 0}, ss = {0, 0, 0, 0};
  for (int tc = 0; tc < 8; tc++) {
    const float* p = partials + (size_t)(b * 8 + tc) * 2 * ND;
    float4 p1 = *(const float4*)(p + tid * 4);
    float4 p2 = *(const float4*)(p + ND + tid * 4);
    sc.x += p1.x; sc.y += p1.y; sc.z += p1.z; sc.w += p1.w;
    ss.x += p2.x; ss.y += p2.y; ss.z += p2.z; ss.w += p2.w;
  }
  *(float4*)(ct + (size_t)b * ND + tid * 4) = sc;
  *(float4*)(cts + (size_t)b * ND + tid * 4) = ss;
}

extern "C" void kernel_launch(void* const* d_in, const int* in_sizes, int n_in,
                              void* d_out, int out_size, void* d_ws, size_t ws_size,
                              hipStream_t stream) {
  const float* s_t_hat = (const float*)d_in[0];
  const float* enc_out  = (const float*)d_in[1];
  const float* enc_feat = (const float*)d_in[2];
  const float* mask     = (const float*)d_in[3];
  const float* cov      = (const float*)d_in[4];
  const float* r_i      = (const float*)d_in[5];
  const float* Wsw      = (const float*)d_in[6];
  const float* Wsb      = (const float*)d_in[7];
  const float* Wc       = (const float*)d_in[8];
  const float* vw       = (const float*)d_in[9];
  const float* Wr       = (const float*)d_in[10];

  float* out    = (float*)d_out;
  float* ct     = out;               // [32,1024]
  float* attn   = out + 32768;       // [32,1024]
  float* covnew = out + 65536;       // [32,1024]
  float* cts    = out + 98304;       // [32,1024]
  float* astr   = out + 131072;      // [32,1,1024]

  float* ws       = (float*)d_ws;
  float* dec      = ws;                      // 32768 f
  float* scores   = ws + 32768;              // 32768 f
  float* s2part   = ws + 65536;              // 524288 f
  float* partials = ws + 589824;             // 524288 f (32*8*2*1024)
  short* rb       = (short*)(ws + 1638400);  // 16,777,216 bf16 (33.55 MB)
  short* wb       = rb + 16777216;           // 524,288 bf16 (1.05 MB)
  const size_t NEEDED = 1638400ull * 4 + 16777216ull * 2 + 524288ull * 2; // 41,156,608 B

  k_decfea<<<256, 256, 0, stream>>>(s_t_hat, Wsw, Wsb, dec);
  k_scoresA<<<8192, 256, 0, stream>>>(enc_feat, dec, Wc, vw, cov, scores);
  k_softmaxA<<<BB, 256, 0, stream>>>(scores, mask, cov, attn, covnew);
  if (ws_size >= NEEDED) {
    k_cvt2<<<8448, 256, 0, stream>>>(r_i, Wr, rb, wb);
    k_gemmB7<<<512, 256, 0, stream>>>(rb, wb, dec, vw, s2part);
  } else {
    k_gemmB<<<dim3(256, 8), 256, 0, stream>>>(r_i, Wr, dec, vw, s2part);
  }
  k_softmaxB<<<BB, 256, 0, stream>>>(s2part, mask, astr);
  k_ctx<<<dim3(8, BB), 256, 0, stream>>>(enc_out, attn, astr, partials);
  k_reduce<<<BB, 256, 0, stream>>>(partials, ct, cts);
}

// Round 14
// 171.284 us; speedup vs baseline: 1.6136x; 1.6136x over previous
//
#include <hip/hip_runtime.h>
#include <hip/hip_bf16.h>

static constexpr int BB   = 32;
static constexpr int TKK  = 1024;
static constexpr int ND   = 1024;   // N = 2*H
static constexpr int ADIM = 512;

typedef __attribute__((ext_vector_type(8))) short bf16x8;
typedef __attribute__((ext_vector_type(4))) float f32x4;

__device__ __forceinline__ float fast_tanh(float x) {
  x = fminf(fmaxf(x, -15.f), 15.f);
  float e = __expf(2.f * x);
  return __fdividef(e - 1.f, e + 1.f);
}

__device__ __forceinline__ short f2bf(float x) {  // RNE f32->bf16
  unsigned u = __float_as_uint(x);
  u += 0x7FFF + ((u >> 16) & 1);
  return (short)(u >> 16);
}

__device__ __forceinline__ void gload_lds16(const void* g, void* l) {
  __builtin_amdgcn_global_load_lds(
      (const __attribute__((address_space(1))) unsigned int*)g,
      (__attribute__((address_space(3))) unsigned int*)l, 16, 0, 0);
}

// K0: f32 -> bf16 streaming convert for r_i (8192 blocks) and Wr (256 blocks).
__global__ __launch_bounds__(256) void k_cvt2(const float* __restrict__ r_i,
    const float* __restrict__ Wr, short* __restrict__ rb, short* __restrict__ wb) {
  size_t bid = blockIdx.x;
  const float* src;
  short* dst;
  size_t i;
  if (bid < 8192) { src = r_i; dst = rb; i = bid * 256 + threadIdx.x; }
  else            { src = Wr;  dst = wb; i = (bid - 8192) * 256 + threadIdx.x; }
  float4 a = ((const float4*)src)[2 * i];
  float4 b = ((const float4*)src)[2 * i + 1];
  bf16x8 h;
  h[0] = f2bf(a.x); h[1] = f2bf(a.y); h[2] = f2bf(a.z); h[3] = f2bf(a.w);
  h[4] = f2bf(b.x); h[5] = f2bf(b.y); h[6] = f2bf(b.z); h[7] = f2bf(b.w);
  ((bf16x8*)dst)[i] = h;
}

// K1: dec[b][n] = sum_k s_t_hat[b][k] * Wsw[n][k] + Wsb[n]
__global__ __launch_bounds__(256) void k_decfea(const float* __restrict__ s_t_hat,
    const float* __restrict__ Wsw, const float* __restrict__ Wsb,
    float* __restrict__ dec) {
  int b  = blockIdx.x >> 3;
  int n0 = (blockIdx.x & 7) << 7;
  int w = threadIdx.x >> 6, lane = threadIdx.x & 63;
  const float4* s4 = (const float4*)(s_t_hat + (size_t)b * ND);
  float4 sv0 = s4[lane], sv1 = s4[lane + 64], sv2 = s4[lane + 128], sv3 = s4[lane + 192];
  for (int nn = 0; nn < 32; nn++) {
    int n = n0 + w * 32 + nn;
    const float4* w4 = (const float4*)(Wsw + (size_t)n * ND);
    float4 wa = w4[lane], wb = w4[lane + 64], wc = w4[lane + 128], wd = w4[lane + 192];
    float acc = sv0.x*wa.x + sv0.y*wa.y + sv0.z*wa.z + sv0.w*wa.w
              + sv1.x*wb.x + sv1.y*wb.y + sv1.z*wb.z + sv1.w*wb.w
              + sv2.x*wc.x + sv2.y*wc.y + sv2.z*wc.z + sv2.w*wc.w
              + sv3.x*wd.x + sv3.y*wd.y + sv3.z*wd.z + sv3.w*wd.w;
    #pragma unroll
    for (int off = 32; off; off >>= 1) acc += __shfl_down(acc, off);
    if (lane == 0) dec[b * ND + n] = acc + Wsb[n];
  }
}

// K2: wave-per-row scores: 4 rows/block, in-wave reduce, no LDS/syncthreads.
__global__ __launch_bounds__(256) void k_scoresA(const float* __restrict__ ef,
    const float* __restrict__ dec, const float* __restrict__ Wc,
    const float* __restrict__ vw, const float* __restrict__ cov,
    float* __restrict__ scores) {
  const int bt = blockIdx.x * 4 + (threadIdx.x >> 6);
  const int b  = bt >> 10;
  const int lane = threadIdx.x & 63;
  const float c = cov[bt];
  float s = 0.f;
  #pragma unroll
  for (int q = 0; q < 4; ++q) {
    const int col = q * 256 + lane * 4;
    float4 e = *(const float4*)(ef + (size_t)bt * ND + col);
    float4 d = *(const float4*)(dec + (size_t)b * ND + col);
    float4 w = *(const float4*)(Wc + col);
    float4 v = *(const float4*)(vw + col);
    s += v.x * fast_tanh(e.x + d.x + c * w.x)
       + v.y * fast_tanh(e.y + d.y + c * w.y)
       + v.z * fast_tanh(e.z + d.z + c * w.z)
       + v.w * fast_tanh(e.w + d.w + c * w.w);
  }
  #pragma unroll
  for (int off = 32; off; off >>= 1) s += __shfl_down(s, off);
  if (lane == 0) scores[bt] = s;
}

// K3: attn = e^{s-max}*mask / sum(e^{s-max}*mask);  covnew = cov + attn
__global__ __launch_bounds__(256) void k_softmaxA(const float* __restrict__ scores,
    const float* __restrict__ mask, const float* __restrict__ cov,
    float* __restrict__ attn, float* __restrict__ covnew) {
  __shared__ float sb[4];
  int b = blockIdx.x, tid = threadIdx.x;
  float4 s = *(const float4*)(scores + (size_t)b * TKK + tid * 4);
  float m = fmaxf(fmaxf(s.x, s.y), fmaxf(s.z, s.w));
  #pragma unroll
  for (int off = 32; off; off >>= 1) m = fmaxf(m, __shfl_down(m, off));
  if ((tid & 63) == 0) sb[tid >> 6] = m;
  __syncthreads();
  m = fmaxf(fmaxf(sb[0], sb[1]), fmaxf(sb[2], sb[3]));
  float4 mk = *(const float4*)(mask + (size_t)b * TKK + tid * 4);
  float4 e;
  e.x = __expf(s.x - m) * mk.x;
  e.y = __expf(s.y - m) * mk.y;
  e.z = __expf(s.z - m) * mk.z;
  e.w = __expf(s.w - m) * mk.w;
  float sum = e.x + e.y + e.z + e.w;
  #pragma unroll
  for (int off = 32; off; off >>= 1) sum += __shfl_down(sum, off);
  __syncthreads();
  if ((tid & 63) == 0) sb[tid >> 6] = sum;
  __syncthreads();
  float inv = __fdividef(1.f, sb[0] + sb[1] + sb[2] + sb[3]);
  float4 a = {e.x * inv, e.y * inv, e.z * inv, e.w * inv};
  *(float4*)(attn + (size_t)b * TKK + tid * 4) = a;
  float4 c = *(const float4*)(cov + (size_t)b * TKK + tid * 4);
  float4 cn = {c.x + a.x, c.y + a.y, c.z + a.z, c.w + a.w};
  *(float4*)(covnew + (size_t)b * TKK + tid * 4) = cn;
}

// K4 (R8 revert, session best): 128x128 tile, BK=32, 3-slot LDS ring
// (2 tiles in flight, counted vmcnt(8)), XCD-chunked block swizzle,
// verified 0-conflict XOR chunk swizzle.
__global__ __launch_bounds__(256) void k_gemmB3(const short* __restrict__ rb,
    const short* __restrict__ wb, const float* __restrict__ dec,
    const float* __restrict__ vw, float* __restrict__ part) {
  __shared__ __align__(16) short As[3][128 * 32];
  __shared__ __align__(16) short Bs[3][128 * 32];
  const int tid = threadIdx.x;
  const int lane = tid & 63, wv = tid >> 6;
  const int wm = wv >> 1, wn = wv & 1;
  const int g = lane >> 4, cl = lane & 15;
  const int bid = blockIdx.x;
  const int swz = (bid & 7) * 256 + (bid >> 3);   // XCD-bijective (2048 % 8 == 0)
  const int mchunk = swz >> 3, nchunk = swz & 7;
  const int b  = mchunk >> 3;
  const int t0 = (mchunk & 7) * 128;
  const int n0 = nchunk * 128;
  const int lrow4 = lane >> 2;                              // 0..15
  const int sck   = ((lane & 3) ^ ((lane >> 3) & 3)) * 8;   // pre-swizzled src k-off
  const short* Agbase = rb + (size_t)(b * TKK + t0) * ADIM;
  const short* Bgbase = wb + (size_t)n0 * ADIM;
  const int rdsw = (g ^ ((cl >> 1) & 3)) * 8;               // read-side phys k-off

  f32x4 acc[4][4];
  #pragma unroll
  for (int m = 0; m < 4; ++m)
    #pragma unroll
    for (int n = 0; n < 4; ++n) acc[m][n] = (f32x4){0.f, 0.f, 0.f, 0.f};

  auto stage = [&](int buf, int kc) {
    const int k0 = kc * 32;
    #pragma unroll
    for (int p = 0; p < 2; ++p) {
      const int rowc = p * 64 + wv * 16;        // wave-uniform 16-row chunk (1 KB)
      const int row  = rowc + lrow4;            // per-lane row
      gload_lds16(Agbase + (size_t)row * ADIM + k0 + sck, &As[buf][rowc * 32]);
      gload_lds16(Bgbase + (size_t)row * ADIM + k0 + sck, &Bs[buf][rowc * 32]);
    }
  };

  stage(0, 0);                       // 4 loads in flight
  stage(1, 1);                       // 8 in flight
  for (int kc = 0; kc < 16; ++kc) {
    if (kc < 14) {
      stage((kc + 2) % 3, kc + 2);   // +4 -> 12 in flight
      asm volatile("s_waitcnt vmcnt(8)" ::: "memory");  // tile kc landed; kc+1,kc+2 fly
    } else if (kc == 14) {
      asm volatile("s_waitcnt vmcnt(4)" ::: "memory");  // tile 14 landed; 15 flies
    } else {
      asm volatile("s_waitcnt vmcnt(0)" ::: "memory");  // tile 15 landed
    }
    __builtin_amdgcn_s_barrier();    // all waves' tile-kc portions written
    const int cur = kc % 3;
    bf16x8 af[4], bfr[4];
    #pragma unroll
    for (int m = 0; m < 4; ++m)
      af[m] = *(const bf16x8*)&As[cur][(wm * 64 + m * 16 + cl) * 32 + rdsw];
    #pragma unroll
    for (int n = 0; n < 4; ++n)
      bfr[n] = *(const bf16x8*)&Bs[cur][(wn * 64 + n * 16 + cl) * 32 + rdsw];
    #pragma unroll
    for (int m = 0; m < 4; ++m)
      #pragma unroll
      for (int n = 0; n < 4; ++n)
        acc[m][n] = __builtin_amdgcn_mfma_f32_16x16x32_bf16(af[m], bfr[n], acc[m][n], 0, 0, 0);
    __builtin_amdgcn_s_barrier();    // reads of slot cur done before next stage into it
  }

  // epilogue: C/D frag layout col=lane&15, row=(lane>>4)*4+reg
  float vvv[4], ddd[4];
  #pragma unroll
  for (int n = 0; n < 4; ++n) {
    const int col = n0 + wn * 64 + n * 16 + cl;
    vvv[n] = vw[col];
    ddd[n] = dec[b * ND + col];
  }
  #pragma unroll
  for (int m = 0; m < 4; ++m) {
    #pragma unroll
    for (int r = 0; r < 4; ++r) {
      float s = 0.f;
      #pragma unroll
      for (int n = 0; n < 4; ++n)
        s += vvv[n] * fast_tanh(acc[m][n][r] + ddd[n]);
      #pragma unroll
      for (int off = 1; off < 16; off <<= 1) s += __shfl_xor(s, off);
      if (cl == 0) {
        const int rowg = b * TKK + t0 + wm * 64 + m * 16 + g * 4 + r;
        part[(size_t)rowg * 16 + nchunk * 2 + wn] = s;
      }
    }
  }
}

// K4 fallback (reg-staged cvt in-kernel) — used only if ws too small for bf16 copies.
__global__ __launch_bounds__(256) void k_gemmB(const float* __restrict__ r_i,
    const float* __restrict__ Wr, const float* __restrict__ dec,
    const float* __restrict__ vw, float* __restrict__ part) {
  __shared__ short As[128 * 64];
  __shared__ short Bs[128 * 64];
  const int tid = threadIdx.x;
  const int lane = tid & 63, wv = tid >> 6;
  const int wm = wv >> 1, wn = wv & 1;
  const int g = lane >> 4, cl = lane & 15;
  const int mchunk = blockIdx.x, nchunk = blockIdx.y;
  const int b  = mchunk >> 3;
  const int t0 = (mchunk & 7) * 128;
  const int n0 = nchunk * 128;
  const float* Ag = r_i + (size_t)(b * TKK + t0) * ADIM;
  const float* Bg = Wr + (size_t)n0 * ADIM;
  const int srow = tid >> 3, skk = (tid & 7) * 8;

  f32x4 acc[4][4];
  #pragma unroll
  for (int m = 0; m < 4; ++m)
    #pragma unroll
    for (int n = 0; n < 4; ++n) acc[m][n] = (f32x4){0.f, 0.f, 0.f, 0.f};

  for (int kc = 0; kc < 8; ++kc) {
    const int k0 = kc * 64;
    __syncthreads();
    #pragma unroll
    for (int dit = 0; dit < 4; ++dit) {
      const int row = dit * 32 + srow;
      const float* sa = Ag + (size_t)row * ADIM + k0 + skk;
      float4 a0 = *(const float4*)sa, a1 = *(const float4*)(sa + 4);
      bf16x8 ha;
      ha[0]=f2bf(a0.x); ha[1]=f2bf(a0.y); ha[2]=f2bf(a0.z); ha[3]=f2bf(a0.w);
      ha[4]=f2bf(a1.x); ha[5]=f2bf(a1.y); ha[6]=f2bf(a1.z); ha[7]=f2bf(a1.w);
      *(bf16x8*)&As[row * 64 + skk] = ha;
      const float* sbp = Bg + (size_t)row * ADIM + k0 + skk;
      float4 b0 = *(const float4*)sbp, b1 = *(const float4*)(sbp + 4);
      bf16x8 hb;
      hb[0]=f2bf(b0.x); hb[1]=f2bf(b0.y); hb[2]=f2bf(b0.z); hb[3]=f2bf(b0.w);
      hb[4]=f2bf(b1.x); hb[5]=f2bf(b1.y); hb[6]=f2bf(b1.z); hb[7]=f2bf(b1.w);
      *(bf16x8*)&Bs[row * 64 + skk] = hb;
    }
    __syncthreads();
    #pragma unroll
    for (int kf = 0; kf < 2; ++kf) {
      bf16x8 af[4], bfr[4];
      #pragma unroll
      for (int m = 0; m < 4; ++m)
        af[m] = *(const bf16x8*)&As[(wm * 64 + m * 16 + cl) * 64 + kf * 32 + g * 8];
      #pragma unroll
      for (int n = 0; n < 4; ++n)
        bfr[n] = *(const bf16x8*)&Bs[(wn * 64 + n * 16 + cl) * 64 + kf * 32 + g * 8];
      #pragma unroll
      for (int m = 0; m < 4; ++m)
        #pragma unroll
        for (int n = 0; n < 4; ++n)
          acc[m][n] = __builtin_amdgcn_mfma_f32_16x16x32_bf16(af[m], bfr[n], acc[m][n], 0, 0, 0);
    }
  }
  float vvv[4], ddd[4];
  #pragma unroll
  for (int n = 0; n < 4; ++n) {
    const int col = n0 + wn * 64 + n * 16 + cl;
    vvv[n] = vw[col];
    ddd[n] = dec[b * ND + col];
  }
  #pragma unroll
  for (int m = 0; m < 4; ++m) {
    #pragma unroll
    for (int r = 0; r < 4; ++r) {
      float s = 0.f;
      #pragma unroll
      for (int n = 0; n < 4; ++n)
        s += vvv[n] * fast_tanh(acc[m][n][r] + ddd[n]);
      #pragma unroll
      for (int off = 1; off < 16; off <<= 1) s += __shfl_xor(s, off);
      if (cl == 0) {
        const int rowg = b * TKK + t0 + wm * 64 + m * 16 + g * 4 + r;
        part[(size_t)rowg * 16 + nchunk * 2 + wn] = s;
      }
    }
  }
}

// K5: s2 = sum of 16 partials; a_struct = e^{s2-max}*mask / sum(e^{s2-max})
__global__ __launch_bounds__(256) void k_softmaxB(const float* __restrict__ part,
    const float* __restrict__ mask, float* __restrict__ astruct) {
  __shared__ float sb[4];
  int b = blockIdx.x, tid = threadIdx.x;
  float sv[4];
  #pragma unroll
  for (int tt = 0; tt < 4; ++tt) {
    const float4* pp = (const float4*)(part + ((size_t)b * TKK + tid * 4 + tt) * 16);
    float4 q0 = pp[0], q1 = pp[1], q2 = pp[2], q3 = pp[3];
    sv[tt] = q0.x+q0.y+q0.z+q0.w + q1.x+q1.y+q1.z+q1.w
           + q2.x+q2.y+q2.z+q2.w + q3.x+q3.y+q3.z+q3.w;
  }
  float m = fmaxf(fmaxf(sv[0], sv[1]), fmaxf(sv[2], sv[3]));
  #pragma unroll
  for (int off = 32; off; off >>= 1) m = fmaxf(m, __shfl_down(m, off));
  if ((tid & 63) == 0) sb[tid >> 6] = m;
  __syncthreads();
  m = fmaxf(fmaxf(sb[0], sb[1]), fmaxf(sb[2], sb[3]));
  float e0 = __expf(sv[0] - m), e1 = __expf(sv[1] - m);
  float e2 = __expf(sv[2] - m), e3 = __expf(sv[3] - m);
  float sum = e0 + e1 + e2 + e3;
  #pragma unroll
  for (int off = 32; off; off >>= 1) sum += __shfl_down(sum, off);
  __syncthreads();
  if ((tid & 63) == 0) sb[tid >> 6] = sum;
  __syncthreads();
  float inv = __fdividef(1.f, sb[0] + sb[1] + sb[2] + sb[3]);
  float4 mk = *(const float4*)(mask + (size_t)b * TKK + tid * 4);
  float4 a = {e0 * mk.x * inv, e1 * mk.y * inv, e2 * mk.z * inv, e3 * mk.w * inv};
  *(float4*)(astruct + (size_t)b * TKK + tid * 4) = a;
}

// K6: partial contexts over t-chunks of 128; both attention vectors, one enc pass.
__global__ __launch_bounds__(256) void k_ctx(const float* __restrict__ enc,
    const float* __restrict__ attn, const float* __restrict__ astr,
    float* __restrict__ partials) {
  int tc = blockIdx.x, b = blockIdx.y;     // tc 0..7
  int tid = threadIdx.x, lane = tid & 63;
  const float4* e4 = (const float4*)(enc + (size_t)(b * TKK + tc * 128) * ND);
  float4 ac = {0, 0, 0, 0}, as = {0, 0, 0, 0};
  #pragma unroll
  for (int h = 0; h < 2; ++h) {
    float a1v = attn[(size_t)b * TKK + tc * 128 + h * 64 + lane];
    float a2v = astr[(size_t)b * TKK + tc * 128 + h * 64 + lane];
    #pragma unroll 4
    for (int m = 0; m < 64; m++) {
      float a1 = __shfl(a1v, m), a2 = __shfl(a2v, m);
      float4 ev = e4[(size_t)(h * 64 + m) * 256 + tid];
      ac.x += a1 * ev.x; ac.y += a1 * ev.y; ac.z += a1 * ev.z; ac.w += a1 * ev.w;
      as.x += a2 * ev.x; as.y += a2 * ev.y; as.z += a2 * ev.z; as.w += a2 * ev.w;
    }
  }
  float* p = partials + (size_t)(b * 8 + tc) * 2 * ND;
  *(float4*)(p + tid * 4) = ac;
  *(float4*)(p + ND + tid * 4) = as;
}

// K7: sum 8 t-chunk partials -> c_t, c_t_struct
__global__ __launch_bounds__(256) void k_reduce(const float* __restrict__ partials,
    float* __restrict__ ct, float* __restrict__ cts) {
  int b = blockIdx.x, tid = threadIdx.x;
  float4 sc = {0, 0, 0, 0}, ss = {0, 0, 0, 0};
  for (int tc = 0; tc < 8; tc++) {
    const float* p = partials + (size_t)(b * 8 + tc) * 2 * ND;
    float4 p1 = *(const float4*)(p + tid * 4);
    float4 p2 = *(const float4*)(p + ND + tid * 4);
    sc.x += p1.x; sc.y += p1.y; sc.z += p1.z; sc.w += p1.w;
    ss.x += p2.x; ss.y += p2.y; ss.z += p2.z; ss.w += p2.w;
  }
  *(float4*)(ct + (size_t)b * ND + tid * 4) = sc;
  *(float4*)(cts + (size_t)b * ND + tid * 4) = ss;
}

extern "C" void kernel_launch(void* const* d_in, const int* in_sizes, int n_in,
                              void* d_out, int out_size, void* d_ws, size_t ws_size,
                              hipStream_t stream) {
  const float* s_t_hat = (const float*)d_in[0];
  const float* enc_out  = (const float*)d_in[1];
  const float* enc_feat = (const float*)d_in[2];
  const float* mask     = (const float*)d_in[3];
  const float* cov      = (const float*)d_in[4];
  const float* r_i      = (const float*)d_in[5];
  const float* Wsw      = (const float*)d_in[6];
  const float* Wsb      = (const float*)d_in[7];
  const float* Wc       = (const float*)d_in[8];
  const float* vw       = (const float*)d_in[9];
  const float* Wr       = (const float*)d_in[10];

  float* out    = (float*)d_out;
  float* ct     = out;               // [32,1024]
  float* attn   = out + 32768;       // [32,1024]
  float* covnew = out + 65536;       // [32,1024]
  float* cts    = out + 98304;       // [32,1024]
  float* astr   = out + 131072;      // [32,1,1024]

  float* ws       = (float*)d_ws;
  float* dec      = ws;                      // 32768 f
  float* scores   = ws + 32768;              // 32768 f
  float* s2part   = ws + 65536;              // 524288 f
  float* partials = ws + 589824;             // 524288 f (32*8*2*1024)
  short* rb       = (short*)(ws + 1638400);  // 16,777,216 bf16 (33.55 MB)
  short* wb       = rb + 16777216;           // 524,288 bf16 (1.05 MB)
  const size_t NEEDED = 1638400ull * 4 + 16777216ull * 2 + 524288ull * 2; // 41,156,608 B

  k_decfea<<<256, 256, 0, stream>>>(s_t_hat, Wsw, Wsb, dec);
  k_scoresA<<<8192, 256, 0, stream>>>(enc_feat, dec, Wc, vw, cov, scores);
  k_softmaxA<<<BB, 256, 0, stream>>>(scores, mask, cov, attn, covnew);
  if (ws_size >= NEEDED) {
    k_cvt2<<<8448, 256, 0, stream>>>(r_i, Wr, rb, wb);
    k_gemmB3<<<2048, 256, 0, stream>>>(rb, wb, dec, vw, s2part);
  } else {
    k_gemmB<<<dim3(256, 8), 256, 0, stream>>>(r_i, Wr, dec, vw, s2part);
  }
  k_softmaxB<<<BB, 256, 0, stream>>>(s2part, mask, astr);
  k_ctx<<<dim3(8, BB), 256, 0, stream>>>(enc_out, attn, astr, partials);
  k_reduce<<<BB, 256, 0, stream>>>(partials, ct, cts);
}